// Round 8
// baseline (580.461 us; speedup 1.0000x reference)
//
#include <hip/hip_runtime.h>
#include <cstdint>

// HistogramLoss via coarse empirical-CDF tables (LDS histograms) + per-input-bin linear
// map (AB table) + exact tail handling in small side arrays.
// matched[i] = sorted(target)[count(input <= input[i]) - 1], loss = mean((matched-input)^2)
//
// Round-7 finding applied here: 128B-contiguous-per-lane layout made every STORE
// instruction a 64-lane x 16B scatter at 128B stride -> partial-line RMW at L2/HBM
// (WRITE 66->192 MB, FETCH 66->162 MB). Loads were fine (lines fully consumed via L1).
// Fix: INTERLEAVED chunk ownership -- thread t owns float4 chunks {c0 + j*256}, so each
// load/store instruction is 64x16B CONTIGUOUS (full lines), while each thread still
// issues up to 8 independent loads (the R6-proven in-flight lever, ~1.9 TB/s).

#define NBINS    8192u              // uniform bins over [-16, 16)
#define HGX      512u               // hist blocks per histogram
#define KIN      2048u              // input tail rank cutoff (per side)
#define KTG      4096u              // target tail rank cutoff (per side)

__device__ __forceinline__ void bin_and_frac(float x, unsigned& b, float& frac) {
    float d = __builtin_fmaf(x, 256.0f, 4096.0f);      // (x+16)*256, one rounding, monotone
    d = fminf(fmaxf(d, 0.0f), 8191.999f);
    unsigned bb = (unsigned)d;
    b = bb;
    frac = d - (float)bb;
}

// LDS-private histogram; merge non-zero bins straight into global H.
// grid (HGX, 2): y==0 -> input -> H[0:NBINS], y==1 -> target -> H[NBINS:2*NBINS].
// Interleaved: block sweep covers 4096 contiguous chunks; thread t owns {base + j*512}.
__global__ __launch_bounds__(512, 4) void hist_kernel(const float* __restrict__ in,
                                                      const float* __restrict__ tg,
                                                      unsigned* __restrict__ H, unsigned n4) {
    __shared__ unsigned h[NBINS];
    for (unsigned i = threadIdx.x; i < NBINS; i += 512) h[i] = 0;
    __syncthreads();
    const float* x = blockIdx.y ? tg : in;
    unsigned* Hh = H + blockIdx.y * NBINS;
    unsigned step = gridDim.x * 4096u;
    for (unsigned base = blockIdx.x * 4096u + threadIdx.x; base < n4; base += step) {
        float4 a[8];
        bool ok[8];
        #pragma unroll
        for (int j = 0; j < 8; j++) {                    // 8 coalesced loads in flight
            unsigned c = base + (unsigned)j * 512u;
            ok[j] = (c < n4);
            a[j] = ((const float4*)x)[ok[j] ? c : 0u];
        }
        #pragma unroll
        for (int j = 0; j < 8; j++) {
            if (!ok[j]) continue;
            float4 v = a[j];
            unsigned b; float f;
            bin_and_frac(v.x, b, f); atomicAdd(&h[b], 1u);
            bin_and_frac(v.y, b, f); atomicAdd(&h[b], 1u);
            bin_and_frac(v.z, b, f); atomicAdd(&h[b], 1u);
            bin_and_frac(v.w, b, f); atomicAdd(&h[b], 1u);
        }
    }
    __syncthreads();
    for (unsigned i = threadIdx.x; i < NBINS; i += 512) {
        unsigned v = h[i];
        if (v) atomicAdd(&Hh[i], v);        // spread-address atomics, fire-and-forget
    }
}

// Exclusive scan of one 8192-bin histogram per block -> C[NBINS+1]. grid = 2 blocks.
__global__ void scan_kernel(const unsigned* __restrict__ H, unsigned* __restrict__ C) {
    __shared__ unsigned s[1024];
    const unsigned* h = H + blockIdx.x * NBINS;
    unsigned* c = C + blockIdx.x * (NBINS + 1);
    unsigned base = threadIdx.x * 8;
    unsigned v[8]; unsigned own = 0;
    #pragma unroll
    for (int k = 0; k < 8; k++) { v[k] = h[base + k]; own += v[k]; }
    s[threadIdx.x] = own; __syncthreads();
    for (unsigned off = 1; off < 1024; off <<= 1) {
        unsigned t = (threadIdx.x >= off) ? s[threadIdx.x - off] : 0u;
        __syncthreads();
        s[threadIdx.x] += t;
        __syncthreads();
    }
    unsigned ex = s[threadIdx.x] - own;
    #pragma unroll
    for (int k = 0; k < 8; k++) { unsigned t = v[k]; c[base + k] = ex; ex += t; }
    if (threadIdx.x == 1023) c[NBINS] = s[1023];
}

// Per-input-bin linear map: matched(frac) = A[b] + B[b]*frac. Tail boundary bins for input
// (hdr[0:2]) and target (hdr[2:4]). All-zero init: bhi stored as (8192-b) under atomicMax,
// decoded as bhi = 8192 - hdr[odd]; hdr==0 -> bhi=8192 -> no upper tail (b<=8191 < 8192).
__global__ void buildAB_kernel(const unsigned* __restrict__ Cin, const unsigned* __restrict__ Ctg,
                               float2* __restrict__ AB, int* __restrict__ hdr, unsigned n) {
    unsigned b = blockIdx.x * blockDim.x + threadIdx.x;
    if (b >= NBINS) return;
    unsigned r0 = Cin[b], r1 = Cin[b + 1];
    if (r1 <= KIN) atomicMax(&hdr[0], (int)b);                 // input blo
    if (r0 >= n - KIN) atomicMax(&hdr[1], (int)(8192u - b));   // input bhi (encoded)
    unsigned t0 = Ctg[b], t1 = Ctg[b + 1];
    if (t1 <= KTG) atomicMax(&hdr[2], (int)b);                 // target blo (whole-bin, rank-closed)
    if (t0 >= n - KTG) atomicMax(&hdr[3], (int)(8192u - b));   // target bhi (encoded)
    if (r1 == r0) { AB[b] = make_float2(0.f, 0.f); return; }   // empty bin, never accessed for real
    const float w = 32.0f / (float)NBINS;
    float v[2];
    unsigned rr[2] = {r0, r1};
    #pragma unroll
    for (int k = 0; k < 2; k++) {
        unsigned r = rr[k]; if (r > n - 1) r = n - 1;
        unsigned lo = 0, hi = NBINS;                            // Ctg[lo] <= r < Ctg[hi]
        while (hi - lo > 1) { unsigned mid = (lo + hi) >> 1; if (Ctg[mid] <= r) lo = mid; else hi = mid; }
        unsigned c0 = Ctg[lo], c1 = Ctg[lo + 1];
        v[k] = -16.0f + (float)lo * w + w * ((float)(r - c0 + 1) / (float)(c1 - c0));
    }
    AB[b] = make_float2(v[0], v[1] - v[0]);
}

// Exact target order statistics into small arrays Tlo[r] (ranks [0,m)) and
// Thi[KTG-1-...] (top ranks). grid (4, 2): blockIdx.y = side, one j per thread.
__global__ void exact_target_kernel(const float* __restrict__ tg_lo, const float* __restrict__ tg_hi,
                                    const unsigned* __restrict__ ctrs,
                                    float* __restrict__ Tlo, float* __restrict__ Thi) {
    __shared__ __align__(16) float v[KTG];
    int side = blockIdx.y;
    const float* src = side ? tg_hi : tg_lo;
    unsigned m = ctrs[side ? 3 : 2];
    if (m > KTG) m = KTG;
    float sgn = side ? -1.f : 1.f;
    for (unsigned k = threadIdx.x; k < m; k += 1024) v[k] = sgn * src[k];
    __syncthreads();
    unsigned j = blockIdx.x * 1024 + threadIdx.x;
    if (j >= m) return;
    float y = v[j];
    unsigned lt = 0, le = 0;
    unsigned m4 = m & ~3u;
    for (unsigned k = 0; k < m4; k += 4) {
        float4 z = *(const float4*)&v[k];
        lt += (z.x < y) + (z.y < y) + (z.z < y) + (z.w < y);
        le += (z.x <= y) + (z.y <= y) + (z.z <= y) + (z.w <= y);
    }
    for (unsigned k = m4; k < m; k++) { lt += (v[k] < y); le += (v[k] <= y); }
    float yo = sgn * y;
    if (side) {
        for (unsigned idx = KTG - le; idx < KTG - lt; idx++) Thi[idx] = yo;  // global rank n-KTG+idx
    } else {
        for (unsigned r = lt; r < le; r++) Tlo[r] = yo;
    }
}

// Fused main pass. grid (n4/2048, 2), 256 threads. Thread t owns chunks {c0 + j*256},
// j=0..7: every load/store instruction is a contiguous 1KB wave access, 8 loads in flight.
//  y==0: interp-match (AB gathers from L2) + per-wave loss partials; collect input tails.
//  y==1: collect target tail elements via threshold-bin compares.
__global__ __launch_bounds__(256, 8) void matchcollect_kernel(
        const float* __restrict__ input, const float* __restrict__ target,
        const float2* __restrict__ AB, const int* __restrict__ hdr,
        float* __restrict__ vlo, unsigned* __restrict__ ilo,
        float* __restrict__ vhi, unsigned* __restrict__ ihi,
        float* __restrict__ tg_lo, float* __restrict__ tg_hi,
        unsigned* __restrict__ ctrs,
        float* __restrict__ out, float* __restrict__ bpart,
        unsigned n) {
    unsigned n4 = n >> 2;
    unsigned c0 = blockIdx.x * 2048u + threadIdx.x;

    if (blockIdx.y == 1) {
        int blo = hdr[2], bhi = 8192 - hdr[3];
        float4 a[8]; bool ok[8];
        #pragma unroll
        for (int j = 0; j < 8; j++) {                    // 8 coalesced loads in flight
            unsigned c = c0 + (unsigned)j * 256u;
            ok[j] = (c < n4);
            a[j] = ((const float4*)target)[ok[j] ? c : 0u];
        }
        #pragma unroll
        for (int g = 0; g < 2; g++) {
            float xs[16];
            #pragma unroll
            for (int jj = 0; jj < 4; jj++) {
                float4 v = a[4 * g + jj];
                xs[4 * jj] = v.x; xs[4 * jj + 1] = v.y; xs[4 * jj + 2] = v.z; xs[4 * jj + 3] = v.w;
            }
            bool lo16[16], hi16[16]; bool any = false;
            #pragma unroll
            for (int k = 0; k < 16; k++) {
                unsigned b; float f;
                bin_and_frac(xs[k], b, f);
                bool okk = ok[4 * g + (k >> 2)];
                lo16[k] = okk && ((int)b <= blo);
                hi16[k] = okk && ((int)b >= bhi);
                any = any || lo16[k] || hi16[k];
            }
            if (any) {
                #pragma unroll
                for (int k = 0; k < 16; k++) {
                    if (lo16[k]) { unsigned p2 = atomicAdd(&ctrs[2], 1u); tg_lo[p2] = xs[k]; }
                    else if (hi16[k]) { unsigned p2 = atomicAdd(&ctrs[3], 1u); tg_hi[p2] = xs[k]; }
                }
            }
        }
        return;
    }

    int blo = hdr[0], bhi = 8192 - hdr[1];
    float acc = 0.f;
    {
        float4 a[8]; bool ok[8];
        #pragma unroll
        for (int j = 0; j < 8; j++) {                    // 8 coalesced loads in flight
            unsigned c = c0 + (unsigned)j * 256u;
            ok[j] = (c < n4);
            a[j] = ((const float4*)input)[ok[j] ? c : 0u];
        }
        #pragma unroll
        for (int g = 0; g < 2; g++) {
            float xs[16];
            #pragma unroll
            for (int jj = 0; jj < 4; jj++) {
                float4 v = a[4 * g + jj];
                xs[4 * jj] = v.x; xs[4 * jj + 1] = v.y; xs[4 * jj + 2] = v.z; xs[4 * jj + 3] = v.w;
            }
            unsigned b[16]; float fr[16];
            #pragma unroll
            for (int k = 0; k < 16; k++) bin_and_frac(xs[k], b[k], fr[k]);
            float m[16];
            #pragma unroll
            for (int h = 0; h < 2; h++) {                // two sub-groups of 8 AB gathers
                float2 ab[8];
                #pragma unroll
                for (int k = 0; k < 8; k++) ab[k] = AB[b[8 * h + k]];
                #pragma unroll
                for (int k = 0; k < 8; k++)
                    m[8 * h + k] = __builtin_fmaf(ab[k].y, fr[8 * h + k], ab[k].x);
            }
            bool tl[16]; bool any = false;
            #pragma unroll
            for (int k = 0; k < 16; k++) {
                bool okk = ok[4 * g + (k >> 2)];
                tl[k] = ((int)b[k] <= blo) || ((int)b[k] >= bhi);
                any = any || (okk && tl[k]);
                float d = (okk && !tl[k]) ? (m[k] - xs[k]) : 0.f;
                acc = __builtin_fmaf(d, d, acc);
            }
            #pragma unroll
            for (int jj = 0; jj < 4; jj++) {             // coalesced full-line stores
                unsigned c = c0 + (unsigned)(4 * g + jj) * 256u;
                if (c < n4)
                    ((float4*)out)[c] = make_float4(m[4 * jj], m[4 * jj + 1], m[4 * jj + 2], m[4 * jj + 3]);
            }
            if (any) {                                   // rare: tails overwritten later
                #pragma unroll
                for (int k = 0; k < 16; k++) {
                    bool okk = ok[4 * g + (k >> 2)];
                    if (!okk || !tl[k]) continue;
                    unsigned gi = 4u * (c0 + (unsigned)(4 * g + (k >> 2)) * 256u) + (unsigned)(k & 3);
                    if ((int)b[k] <= blo) { unsigned p2 = atomicAdd(&ctrs[0], 1u); vlo[p2] = xs[k]; ilo[p2] = gi; }
                    else                  { unsigned p2 = atomicAdd(&ctrs[1], 1u); vhi[p2] = xs[k]; ihi[p2] = gi; }
                }
            }
        }
    }
    #pragma unroll
    for (int off = 32; off > 0; off >>= 1) acc += __shfl_down(acc, off, 64);
    if ((threadIdx.x & 63) == 0)
        bpart[blockIdx.x * 4 + (threadIdx.x >> 6)] = acc;    // per-wave plain store
}

// Sum the per-wave partials -> *loss (plain store; exact_input atomicAdds after).
__global__ void loss_reduce_kernel(const float* __restrict__ bpart, float* __restrict__ loss,
                                   unsigned nb, unsigned n) {
    float s = 0.f;
    for (unsigned i = threadIdx.x; i < nb; i += 1024) s += bpart[i];
    #pragma unroll
    for (int off = 32; off > 0; off >>= 1) s += __shfl_down(s, off, 64);
    __shared__ float ws[16];
    int w = threadIdx.x >> 6;
    if ((threadIdx.x & 63) == 0) ws[w] = s;
    __syncthreads();
    if (threadIdx.x == 0) {
        float t = 0.f;
        #pragma unroll
        for (int k = 0; k < 16; k++) t += ws[k];
        *loss = t * (1.0f / (float)n);
    }
}

// Exact input tail matching. grid (2, 2): blockIdx.y = side, one j per thread.
// Runs LAST: overwrites the placeholder matched values at tail indices.
__global__ void exact_input_kernel(const float* __restrict__ in_lo_v, const unsigned* __restrict__ in_lo_i,
                                   const float* __restrict__ in_hi_v, const unsigned* __restrict__ in_hi_i,
                                   const unsigned* __restrict__ ctrs,
                                   const float* __restrict__ Tlo, const float* __restrict__ Thi,
                                   float* __restrict__ out, float* __restrict__ loss, unsigned n) {
    __shared__ __align__(16) float v[KIN];
    int side = blockIdx.y;
    const float* sv = side ? in_hi_v : in_lo_v;
    const unsigned* si = side ? in_hi_i : in_lo_i;
    unsigned m = ctrs[side ? 1 : 0];
    if (m > KIN) m = KIN;
    float sgn = side ? -1.f : 1.f;
    for (unsigned k = threadIdx.x; k < m; k += 1024) v[k] = sgn * sv[k];
    __syncthreads();
    unsigned j = blockIdx.x * 1024 + threadIdx.x;
    float d2 = 0.f;
    if (j < m) {
        float y = v[j];
        unsigned lt = 0, le = 0;
        unsigned m4 = m & ~3u;
        for (unsigned k = 0; k < m4; k += 4) {
            float4 z = *(const float4*)&v[k];
            lt += (z.x < y) + (z.y < y) + (z.z < y) + (z.w < y);
            le += (z.x <= y) + (z.y <= y) + (z.z <= y) + (z.w <= y);
        }
        for (unsigned k = m4; k < m; k++) { lt += (v[k] < y); le += (v[k] <= y); }
        // bottom: global rank = le-1 (< KIN <= KTG). top: global rank = n-1-lt -> Thi[KTG-1-lt].
        float mv = side ? Thi[KTG - 1 - lt] : Tlo[le - 1];
        float x = sgn * y;
        out[si[j]] = mv;
        float d = mv - x;
        d2 = d * d;
    }
    #pragma unroll
    for (int off = 32; off > 0; off >>= 1) d2 += __shfl_down(d2, off, 64);
    if ((threadIdx.x & 63) == 0 && d2 != 0.f)
        atomicAdd(loss, d2 * (1.0f / (float)n));
}

extern "C" void kernel_launch(void* const* d_in, const int* in_sizes, int n_in,
                              void* d_out, int out_size, void* d_ws, size_t ws_size,
                              hipStream_t stream) {
    const float* input  = (const float*)d_in[0];
    const float* target = (const float*)d_in[1];
    unsigned n = (unsigned)in_sizes[0];   // 16777216 = 2^24
    float* out  = (float*)d_out;
    float* loss = out + n;

    char* wsb = (char*)d_ws;
    unsigned* H    = (unsigned*)(wsb);                       // 2*NBINS*4 = 64 KB
    unsigned* Cin  = (unsigned*)(wsb + 64 * 1024);           // 2*(NBINS+1)*4
    unsigned* Ctg  = Cin + (NBINS + 1);
    float2*   AB   = (float2*)  (wsb + 160 * 1024);          // 64 KB
    char*     aux  = wsb + 224 * 1024;
    int*      hdr  = (int*)     (aux);                       // 16B [in_blo, enc_in_bhi, tg_blo, enc_tg_bhi]
    unsigned* ctrs = (unsigned*)(aux + 16);                  // 16B [in_lo, in_hi, tg_lo, tg_hi]
    float*    bpart= (float*)   (aux + 64);                  // up to 16384 floats (64 KB)
    char*     tails= aux + 64 + 65536 + 64;
    float*    in_lo_v = (float*)   (tails);
    unsigned* in_lo_i = (unsigned*)(tails + KIN * 4);
    float*    in_hi_v = (float*)   (tails + KIN * 8);
    unsigned* in_hi_i = (unsigned*)(tails + KIN * 12);
    float*    tg_lo   = (float*)   (tails + KIN * 16);
    float*    tg_hi   = (float*)   (tails + KIN * 16 + KTG * 4);
    float*    Tlo     = (float*)   (tails + KIN * 16 + KTG * 8);
    float*    Thi     = (float*)   (tails + KIN * 16 + KTG * 12);

    (void)hipMemsetAsync(H, 0, 2 * NBINS * 4, stream);
    (void)hipMemsetAsync(hdr, 0, 32, stream);                // hdr[4] + ctrs[4], all-zero init
    (void)hipMemsetAsync(loss, 0, 4, stream);

    unsigned n4 = n >> 2;
    unsigned mgx = (n4 + 2047) / 2048;                       // 2048 for n=2^24

    hist_kernel<<<dim3(HGX, 2), 512, 0, stream>>>(input, target, H, n4);
    scan_kernel<<<2, 1024, 0, stream>>>(H, Cin);   // block 0 -> Cin, block 1 -> Ctg
    buildAB_kernel<<<NBINS / 256, 256, 0, stream>>>(Cin, Ctg, AB, hdr, n);

    matchcollect_kernel<<<dim3(mgx, 2), 256, 0, stream>>>(input, target, AB, hdr,
                                                          in_lo_v, in_lo_i, in_hi_v, in_hi_i,
                                                          tg_lo, tg_hi, ctrs, out, bpart, n);
    loss_reduce_kernel<<<1, 1024, 0, stream>>>(bpart, loss, mgx * 4, n);
    exact_target_kernel<<<dim3((KTG + 1023) / 1024, 2), 1024, 0, stream>>>(tg_lo, tg_hi, ctrs, Tlo, Thi);
    exact_input_kernel<<<dim3((KIN + 1023) / 1024, 2), 1024, 0, stream>>>(in_lo_v, in_lo_i, in_hi_v, in_hi_i,
                                                                          ctrs, Tlo, Thi, out, loss, n);
}

// Round 9
// 523.967 us; speedup vs baseline: 1.1078x; 1.1078x over previous
//
#include <hip/hip_runtime.h>
#include <cstdint>

// HistogramLoss via coarse empirical-CDF tables (LDS histograms) + per-input-bin linear
// map (AB table) + exact tail handling in small side arrays.
// matched[i] = sorted(target)[count(input <= input[i]) - 1], loss = mean((matched-input)^2)
//
// Round-8 finding: ALL single-shot deep-ILP variants amplify HBM traffic 2.4-3.6x
// (even with provably full-line coalesced stores) -- L2 evicts under full-grid streaming
// pressure before merge. The grid-stride LOOP structure (R1/R3/R4) is the only
// traffic-clean configuration (132-139 MB). BW, however, scales with in-flight loads
// (R6-R8: 0.93 -> 2.3 TB/s). This revision keeps R3's exact loop+addressing (32B/lane,
// back-to-back covering stores) and raises in-flight INSIDE the loop: software-pipelined
// unroll-2, 4 dwordx4 loads issued (clamped-index, unconditional) before consumption,
// no LDS, launch_bounds(256,8) => VGPR<=64, 8 waves/SIMD. Same treatment for hist.

#define NBINS    8192u              // uniform bins over [-16, 16)
#define HGX      512u               // hist blocks per histogram
#define MGX      2048u              // match / collect blocks per stream
#define KIN      2048u              // input tail rank cutoff (per side)
#define KTG      4096u              // target tail rank cutoff (per side)

__device__ __forceinline__ void bin_and_frac(float x, unsigned& b, float& frac) {
    float d = __builtin_fmaf(x, 256.0f, 4096.0f);      // (x+16)*256, one rounding, monotone
    d = fminf(fmaxf(d, 0.0f), 8191.999f);
    unsigned bb = (unsigned)d;
    b = bb;
    frac = d - (float)bb;
}

__device__ __forceinline__ void hist8(float4 A0, float4 A1, unsigned* h) {
    float xs[8] = {A0.x, A0.y, A0.z, A0.w, A1.x, A1.y, A1.z, A1.w};
    #pragma unroll
    for (int k = 0; k < 8; k++) {
        unsigned b; float f;
        bin_and_frac(xs[k], b, f);
        atomicAdd(&h[b], 1u);
    }
}

// LDS-private histogram; merge non-zero bins straight into global H.
// grid (HGX, 2): y==0 -> input -> H[0:NBINS], y==1 -> target -> H[NBINS:2*NBINS].
// Unroll-2 grid-stride: 4 coalesced dwordx4 loads in flight per thread-iteration.
__global__ __launch_bounds__(512, 8) void hist_kernel(const float* __restrict__ in,
                                                      const float* __restrict__ tg,
                                                      unsigned* __restrict__ H, unsigned n8) {
    __shared__ unsigned h[NBINS];
    for (unsigned i = threadIdx.x; i < NBINS; i += 512) h[i] = 0;
    __syncthreads();
    const float* x = blockIdx.y ? tg : in;
    unsigned* Hh = H + blockIdx.y * NBINS;
    unsigned stride = gridDim.x * 512, stride2 = stride * 2;
    for (unsigned i = blockIdx.x * 512 + threadIdx.x; i < n8; i += stride2) {
        unsigned j = i + stride;
        unsigned jj = (j < n8) ? j : i;                  // clamp -> loads unconditional
        float4 a0 = ((const float4*)x)[2 * i];
        float4 a1 = ((const float4*)x)[2 * i + 1];
        float4 c0 = ((const float4*)x)[2 * jj];          // 4 loads in flight
        float4 c1 = ((const float4*)x)[2 * jj + 1];
        hist8(a0, a1, h);
        if (j < n8) hist8(c0, c1, h);
    }
    __syncthreads();
    for (unsigned i = threadIdx.x; i < NBINS; i += 512) {
        unsigned v = h[i];
        if (v) atomicAdd(&Hh[i], v);        // spread-address atomics, fire-and-forget
    }
}

// Exclusive scan of one 8192-bin histogram per block -> C[NBINS+1]. grid = 2 blocks.
__global__ void scan_kernel(const unsigned* __restrict__ H, unsigned* __restrict__ C) {
    __shared__ unsigned s[1024];
    const unsigned* h = H + blockIdx.x * NBINS;
    unsigned* c = C + blockIdx.x * (NBINS + 1);
    unsigned base = threadIdx.x * 8;
    unsigned v[8]; unsigned own = 0;
    #pragma unroll
    for (int k = 0; k < 8; k++) { v[k] = h[base + k]; own += v[k]; }
    s[threadIdx.x] = own; __syncthreads();
    for (unsigned off = 1; off < 1024; off <<= 1) {
        unsigned t = (threadIdx.x >= off) ? s[threadIdx.x - off] : 0u;
        __syncthreads();
        s[threadIdx.x] += t;
        __syncthreads();
    }
    unsigned ex = s[threadIdx.x] - own;
    #pragma unroll
    for (int k = 0; k < 8; k++) { unsigned t = v[k]; c[base + k] = ex; ex += t; }
    if (threadIdx.x == 1023) c[NBINS] = s[1023];
}

// Per-input-bin linear map: matched(frac) = A[b] + B[b]*frac. Tail boundary bins for input
// (hdr[0:2]) and target (hdr[2:4]). All-zero init: bhi stored as (8192-b) under atomicMax,
// decoded as bhi = 8192 - hdr[odd]; hdr==0 -> bhi=8192 -> no upper tail (b<=8191 < 8192).
__global__ void buildAB_kernel(const unsigned* __restrict__ Cin, const unsigned* __restrict__ Ctg,
                               float2* __restrict__ AB, int* __restrict__ hdr, unsigned n) {
    unsigned b = blockIdx.x * blockDim.x + threadIdx.x;
    if (b >= NBINS) return;
    unsigned r0 = Cin[b], r1 = Cin[b + 1];
    if (r1 <= KIN) atomicMax(&hdr[0], (int)b);                 // input blo
    if (r0 >= n - KIN) atomicMax(&hdr[1], (int)(8192u - b));   // input bhi (encoded)
    unsigned t0 = Ctg[b], t1 = Ctg[b + 1];
    if (t1 <= KTG) atomicMax(&hdr[2], (int)b);                 // target blo (whole-bin, rank-closed)
    if (t0 >= n - KTG) atomicMax(&hdr[3], (int)(8192u - b));   // target bhi (encoded)
    if (r1 == r0) { AB[b] = make_float2(0.f, 0.f); return; }   // empty bin, never accessed for real
    const float w = 32.0f / (float)NBINS;
    float v[2];
    unsigned rr[2] = {r0, r1};
    #pragma unroll
    for (int k = 0; k < 2; k++) {
        unsigned r = rr[k]; if (r > n - 1) r = n - 1;
        unsigned lo = 0, hi = NBINS;                            // Ctg[lo] <= r < Ctg[hi]
        while (hi - lo > 1) { unsigned mid = (lo + hi) >> 1; if (Ctg[mid] <= r) lo = mid; else hi = mid; }
        unsigned c0 = Ctg[lo], c1 = Ctg[lo + 1];
        v[k] = -16.0f + (float)lo * w + w * ((float)(r - c0 + 1) / (float)(c1 - c0));
    }
    AB[b] = make_float2(v[0], v[1] - v[0]);
}

// Exact target order statistics into small arrays Tlo[r] (ranks [0,m)) and
// Thi[KTG-1-...] (top ranks). grid (4, 2): blockIdx.y = side, one j per thread.
__global__ void exact_target_kernel(const float* __restrict__ tg_lo, const float* __restrict__ tg_hi,
                                    const unsigned* __restrict__ ctrs,
                                    float* __restrict__ Tlo, float* __restrict__ Thi) {
    __shared__ __align__(16) float v[KTG];
    int side = blockIdx.y;
    const float* src = side ? tg_hi : tg_lo;
    unsigned m = ctrs[side ? 3 : 2];
    if (m > KTG) m = KTG;
    float sgn = side ? -1.f : 1.f;
    for (unsigned k = threadIdx.x; k < m; k += 1024) v[k] = sgn * src[k];
    __syncthreads();
    unsigned j = blockIdx.x * 1024 + threadIdx.x;
    if (j >= m) return;
    float y = v[j];
    unsigned lt = 0, le = 0;
    unsigned m4 = m & ~3u;
    for (unsigned k = 0; k < m4; k += 4) {
        float4 z = *(const float4*)&v[k];
        lt += (z.x < y) + (z.y < y) + (z.z < y) + (z.w < y);
        le += (z.x <= y) + (z.y <= y) + (z.z <= y) + (z.w <= y);
    }
    for (unsigned k = m4; k < m; k++) { lt += (v[k] < y); le += (v[k] <= y); }
    float yo = sgn * y;
    if (side) {
        for (unsigned idx = KTG - le; idx < KTG - lt; idx++) Thi[idx] = yo;  // global rank n-KTG+idx
    } else {
        for (unsigned r = lt; r < le; r++) Tlo[r] = yo;
    }
}

__device__ __forceinline__ void collect8(float4 A0, float4 A1, int blo, int bhi,
                                         float* __restrict__ tg_lo, float* __restrict__ tg_hi,
                                         unsigned* __restrict__ ctrs) {
    float xs[8] = {A0.x, A0.y, A0.z, A0.w, A1.x, A1.y, A1.z, A1.w};
    bool lo8[8], hi8[8]; bool any = false;
    #pragma unroll
    for (int k = 0; k < 8; k++) {
        unsigned b; float f;
        bin_and_frac(xs[k], b, f);
        lo8[k] = ((int)b <= blo);
        hi8[k] = ((int)b >= bhi);
        any = any || lo8[k] || hi8[k];
    }
    if (any) {
        #pragma unroll
        for (int k = 0; k < 8; k++) {
            if (lo8[k]) { unsigned p = atomicAdd(&ctrs[2], 1u); tg_lo[p] = xs[k]; }
            else if (hi8[k]) { unsigned p = atomicAdd(&ctrs[3], 1u); tg_hi[p] = xs[k]; }
        }
    }
}

__device__ __forceinline__ float match8(float4 A0, float4 A1, unsigned i,
                                        const float2* __restrict__ AB, int blo, int bhi,
                                        float* __restrict__ out,
                                        float* __restrict__ vlo, unsigned* __restrict__ ilo,
                                        float* __restrict__ vhi, unsigned* __restrict__ ihi,
                                        unsigned* __restrict__ ctrs) {
    float xs[8] = {A0.x, A0.y, A0.z, A0.w, A1.x, A1.y, A1.z, A1.w};
    unsigned b[8]; float fr[8];
    #pragma unroll
    for (int k = 0; k < 8; k++) bin_and_frac(xs[k], b[k], fr[k]);
    float2 ab[8];
    #pragma unroll
    for (int k = 0; k < 8; k++) ab[k] = AB[b[k]];        // 8 L2 gathers in flight
    float m[8]; bool tl[8]; bool any = false; float acc = 0.f;
    #pragma unroll
    for (int k = 0; k < 8; k++) {
        m[k] = __builtin_fmaf(ab[k].y, fr[k], ab[k].x);  // tail lanes: harmless placeholder
        tl[k] = ((int)b[k] <= blo) || ((int)b[k] >= bhi);
        any = any || tl[k];
        float d = tl[k] ? 0.f : (m[k] - xs[k]);
        acc = __builtin_fmaf(d, d, acc);
    }
    ((float4*)out)[2 * i]     = make_float4(m[0], m[1], m[2], m[3]);   // back-to-back covering stores
    ((float4*)out)[2 * i + 1] = make_float4(m[4], m[5], m[6], m[7]);
    if (any) {                                           // rare: tails overwritten later
        #pragma unroll
        for (int k = 0; k < 8; k++) {
            if (!tl[k]) continue;
            if ((int)b[k] <= blo) { unsigned p = atomicAdd(&ctrs[0], 1u); vlo[p] = xs[k]; ilo[p] = 8 * i + k; }
            else                  { unsigned p = atomicAdd(&ctrs[1], 1u); vhi[p] = xs[k]; ihi[p] = 8 * i + k; }
        }
    }
    return acc;
}

// Fused main pass. grid (MGX, 2), 256 threads. Unroll-2 grid-stride: both sub-iterations'
// loads (4x dwordx4) issue before any consumption; R3's proven-clean 32B/lane addressing.
//  y==0: interp-match (AB gathers from L2) + per-wave loss partials; collect input tails.
//  y==1: collect target tail elements via threshold-bin compares.
__global__ __launch_bounds__(256, 8) void matchcollect_kernel(
        const float* __restrict__ input, const float* __restrict__ target,
        const float2* __restrict__ AB, const int* __restrict__ hdr,
        float* __restrict__ vlo, unsigned* __restrict__ ilo,
        float* __restrict__ vhi, unsigned* __restrict__ ihi,
        float* __restrict__ tg_lo, float* __restrict__ tg_hi,
        unsigned* __restrict__ ctrs,
        float* __restrict__ out, float* __restrict__ bpart,
        unsigned n) {
    unsigned n8 = n >> 3;
    unsigned stride = gridDim.x * 256, stride2 = stride * 2;
    unsigned i0 = blockIdx.x * 256 + threadIdx.x;

    if (blockIdx.y == 1) {
        int blo = hdr[2], bhi = 8192 - hdr[3];
        for (unsigned i = i0; i < n8; i += stride2) {
            unsigned j = i + stride;
            unsigned jj = (j < n8) ? j : i;              // clamp -> loads unconditional
            float4 a0 = ((const float4*)target)[2 * i];
            float4 a1 = ((const float4*)target)[2 * i + 1];
            float4 c0 = ((const float4*)target)[2 * jj]; // 4 loads in flight
            float4 c1 = ((const float4*)target)[2 * jj + 1];
            collect8(a0, a1, blo, bhi, tg_lo, tg_hi, ctrs);
            if (j < n8) collect8(c0, c1, blo, bhi, tg_lo, tg_hi, ctrs);
        }
        return;
    }

    int blo = hdr[0], bhi = 8192 - hdr[1];
    float acc = 0.f;
    for (unsigned i = i0; i < n8; i += stride2) {
        unsigned j = i + stride;
        unsigned jj = (j < n8) ? j : i;                  // clamp -> loads unconditional
        float4 a0 = ((const float4*)input)[2 * i];
        float4 a1 = ((const float4*)input)[2 * i + 1];
        float4 c0 = ((const float4*)input)[2 * jj];      // 4 loads in flight
        float4 c1 = ((const float4*)input)[2 * jj + 1];
        acc += match8(a0, a1, i, AB, blo, bhi, out, vlo, ilo, vhi, ihi, ctrs);
        if (j < n8)
            acc += match8(c0, c1, j, AB, blo, bhi, out, vlo, ilo, vhi, ihi, ctrs);
    }
    #pragma unroll
    for (int off = 32; off > 0; off >>= 1) acc += __shfl_down(acc, off, 64);
    if ((threadIdx.x & 63) == 0)
        bpart[blockIdx.x * 4 + (threadIdx.x >> 6)] = acc;    // per-wave plain store
}

// Sum the per-wave partials -> *loss (plain store; exact_input atomicAdds after).
__global__ void loss_reduce_kernel(const float* __restrict__ bpart, float* __restrict__ loss,
                                   unsigned nb, unsigned n) {
    float s = 0.f;
    for (unsigned i = threadIdx.x; i < nb; i += 1024) s += bpart[i];
    #pragma unroll
    for (int off = 32; off > 0; off >>= 1) s += __shfl_down(s, off, 64);
    __shared__ float ws[16];
    int w = threadIdx.x >> 6;
    if ((threadIdx.x & 63) == 0) ws[w] = s;
    __syncthreads();
    if (threadIdx.x == 0) {
        float t = 0.f;
        #pragma unroll
        for (int k = 0; k < 16; k++) t += ws[k];
        *loss = t * (1.0f / (float)n);
    }
}

// Exact input tail matching. grid (2, 2): blockIdx.y = side, one j per thread.
// Runs LAST: overwrites the placeholder matched values at tail indices.
__global__ void exact_input_kernel(const float* __restrict__ in_lo_v, const unsigned* __restrict__ in_lo_i,
                                   const float* __restrict__ in_hi_v, const unsigned* __restrict__ in_hi_i,
                                   const unsigned* __restrict__ ctrs,
                                   const float* __restrict__ Tlo, const float* __restrict__ Thi,
                                   float* __restrict__ out, float* __restrict__ loss, unsigned n) {
    __shared__ __align__(16) float v[KIN];
    int side = blockIdx.y;
    const float* sv = side ? in_hi_v : in_lo_v;
    const unsigned* si = side ? in_hi_i : in_lo_i;
    unsigned m = ctrs[side ? 1 : 0];
    if (m > KIN) m = KIN;
    float sgn = side ? -1.f : 1.f;
    for (unsigned k = threadIdx.x; k < m; k += 1024) v[k] = sgn * sv[k];
    __syncthreads();
    unsigned j = blockIdx.x * 1024 + threadIdx.x;
    float d2 = 0.f;
    if (j < m) {
        float y = v[j];
        unsigned lt = 0, le = 0;
        unsigned m4 = m & ~3u;
        for (unsigned k = 0; k < m4; k += 4) {
            float4 z = *(const float4*)&v[k];
            lt += (z.x < y) + (z.y < y) + (z.z < y) + (z.w < y);
            le += (z.x <= y) + (z.y <= y) + (z.z <= y) + (z.w <= y);
        }
        for (unsigned k = m4; k < m; k++) { lt += (v[k] < y); le += (v[k] <= y); }
        // bottom: global rank = le-1 (< KIN <= KTG). top: global rank = n-1-lt -> Thi[KTG-1-lt].
        float mv = side ? Thi[KTG - 1 - lt] : Tlo[le - 1];
        float x = sgn * y;
        out[si[j]] = mv;
        float d = mv - x;
        d2 = d * d;
    }
    #pragma unroll
    for (int off = 32; off > 0; off >>= 1) d2 += __shfl_down(d2, off, 64);
    if ((threadIdx.x & 63) == 0 && d2 != 0.f)
        atomicAdd(loss, d2 * (1.0f / (float)n));
}

extern "C" void kernel_launch(void* const* d_in, const int* in_sizes, int n_in,
                              void* d_out, int out_size, void* d_ws, size_t ws_size,
                              hipStream_t stream) {
    const float* input  = (const float*)d_in[0];
    const float* target = (const float*)d_in[1];
    unsigned n = (unsigned)in_sizes[0];   // 16777216 = 2^24
    float* out  = (float*)d_out;
    float* loss = out + n;

    char* wsb = (char*)d_ws;
    unsigned* H    = (unsigned*)(wsb);                       // 2*NBINS*4 = 64 KB
    unsigned* Cin  = (unsigned*)(wsb + 64 * 1024);           // 2*(NBINS+1)*4
    unsigned* Ctg  = Cin + (NBINS + 1);
    float2*   AB   = (float2*)  (wsb + 160 * 1024);          // 64 KB
    char*     aux  = wsb + 224 * 1024;
    int*      hdr  = (int*)     (aux);                       // 16B [in_blo, enc_in_bhi, tg_blo, enc_tg_bhi]
    unsigned* ctrs = (unsigned*)(aux + 16);                  // 16B [in_lo, in_hi, tg_lo, tg_hi]
    float*    bpart= (float*)   (aux + 64);                  // MGX*4 floats (32 KB)
    char*     tails= aux + 64 + 65536 + 64;
    float*    in_lo_v = (float*)   (tails);
    unsigned* in_lo_i = (unsigned*)(tails + KIN * 4);
    float*    in_hi_v = (float*)   (tails + KIN * 8);
    unsigned* in_hi_i = (unsigned*)(tails + KIN * 12);
    float*    tg_lo   = (float*)   (tails + KIN * 16);
    float*    tg_hi   = (float*)   (tails + KIN * 16 + KTG * 4);
    float*    Tlo     = (float*)   (tails + KIN * 16 + KTG * 8);
    float*    Thi     = (float*)   (tails + KIN * 16 + KTG * 12);

    (void)hipMemsetAsync(H, 0, 2 * NBINS * 4, stream);
    (void)hipMemsetAsync(hdr, 0, 32, stream);                // hdr[4] + ctrs[4], all-zero init
    (void)hipMemsetAsync(loss, 0, 4, stream);

    unsigned n8 = n >> 3;

    hist_kernel<<<dim3(HGX, 2), 512, 0, stream>>>(input, target, H, n8);
    scan_kernel<<<2, 1024, 0, stream>>>(H, Cin);   // block 0 -> Cin, block 1 -> Ctg
    buildAB_kernel<<<NBINS / 256, 256, 0, stream>>>(Cin, Ctg, AB, hdr, n);

    matchcollect_kernel<<<dim3(MGX, 2), 256, 0, stream>>>(input, target, AB, hdr,
                                                          in_lo_v, in_lo_i, in_hi_v, in_hi_i,
                                                          tg_lo, tg_hi, ctrs, out, bpart, n);
    loss_reduce_kernel<<<1, 1024, 0, stream>>>(bpart, loss, MGX * 4, n);
    exact_target_kernel<<<dim3((KTG + 1023) / 1024, 2), 1024, 0, stream>>>(tg_lo, tg_hi, ctrs, Tlo, Thi);
    exact_input_kernel<<<dim3((KIN + 1023) / 1024, 2), 1024, 0, stream>>>(in_lo_v, in_lo_i, in_hi_v, in_hi_i,
                                                                          ctrs, Tlo, Thi, out, loss, n);
}